// Round 3
// baseline (1639.158 us; speedup 1.0000x reference)
//
#include <hip/hip_runtime.h>
#include <math.h>

#define D_    1024
#define H_    16
#define E_    64
#define DF_   4096
#define NL_   3
#define V_    32000
#define B_    2
#define LSEQ_ 2048
#define M_    (B_*LSEQ_)     // 4096 rows
#define QKVW  (3*D_)         // 3072

typedef __attribute__((ext_vector_type(8))) short bf16x8;   // 8 bf16 = 4 VGPR (MFMA operand)
typedef __attribute__((ext_vector_type(4))) float f32x4;
typedef __attribute__((ext_vector_type(4))) unsigned short us4_t;

__device__ __forceinline__ float bfr2f(unsigned short u){ return __uint_as_float(((unsigned)u)<<16); }
__device__ __forceinline__ unsigned short f2bfr(float f){
  unsigned u = __float_as_uint(f);
  u += 0x7fffu + ((u>>16)&1u);          // RNE
  return (unsigned short)(u>>16);
}
__device__ __forceinline__ void gl_lds16(const unsigned short* g, unsigned short* l){
  __builtin_amdgcn_global_load_lds((const __attribute__((address_space(1))) void*)g,
                                   (__attribute__((address_space(3))) void*)l, 16, 0, 0);
}

// ---------------- embedding ----------------
__global__ __launch_bounds__(256) void embed_kernel(const int* __restrict__ tokens,
                                                    const float* __restrict__ tok_emb,
                                                    const float* __restrict__ pos_emb,
                                                    float* __restrict__ x){
  const int r = blockIdx.x, tid = threadIdx.x;
  const int l = r & (LSEQ_-1);
  const int t = tokens[r];
  float4 te = ((const float4*)(tok_emb + (size_t)t*D_))[tid];
  float4 pe = ((const float4*)(pos_emb + (size_t)l*D_))[tid];
  float4 o = {te.x+pe.x, te.y+pe.y, te.z+pe.z, te.w+pe.w};
  ((float4*)(x + (size_t)r*D_))[tid] = o;
}

// ---------------- layernorm ----------------
__global__ __launch_bounds__(256) void ln_kernel(const float* __restrict__ x,
                                                 const float* __restrict__ g,
                                                 const float* __restrict__ b,
                                                 unsigned short* __restrict__ h){
  const int r = blockIdx.x, tid = threadIdx.x;
  const int wave = tid>>6, lane = tid&63;
  float4 v = ((const float4*)(x + (size_t)r*D_))[tid];
  float s  = v.x+v.y+v.z+v.w;
  float s2 = v.x*v.x+v.y*v.y+v.z*v.z+v.w*v.w;
  #pragma unroll
  for (int off=1; off<64; off<<=1){ s += __shfl_xor(s,off); s2 += __shfl_xor(s2,off); }
  __shared__ float red[8];
  if (!lane){ red[wave]=s; red[4+wave]=s2; }
  __syncthreads();
  s  = red[0]+red[1]+red[2]+red[3];
  s2 = red[4]+red[5]+red[6]+red[7];
  const float mean = s*(1.f/D_);
  const float var  = s2*(1.f/D_) - mean*mean;
  const float rstd = rsqrtf(var + 1e-5f);
  const int c0 = tid*4;
  float4 gg = ((const float4*)g)[tid];
  float4 bb = ((const float4*)b)[tid];
  us4_t ov;
  ov[0] = f2bfr((v.x-mean)*rstd*gg.x + bb.x);
  ov[1] = f2bfr((v.y-mean)*rstd*gg.y + bb.y);
  ov[2] = f2bfr((v.z-mean)*rstd*gg.z + bb.z);
  ov[3] = f2bfr((v.w-mean)*rstd*gg.w + bb.w);
  *(us4_t*)&h[(size_t)r*D_ + c0] = ov;
}

// ---------------- transpose+cast: W_f32[K][N] -> WT_bf16[(rowOff+n)][k] ----------------
__global__ __launch_bounds__(256) void transpose_kernel(const float* __restrict__ W,
                                                        unsigned short* __restrict__ WT,
                                                        int N, int K, int rowOff){
  __shared__ unsigned short T[64*65];
  const int n0 = blockIdx.x*64, k0 = blockIdx.y*64;
  const int tid = threadIdx.x;
  const int kr = tid>>2, nc = (tid&3)*16;
  const float* src = W + (size_t)(k0+kr)*N + n0 + nc;
  #pragma unroll
  for (int j0=0;j0<16;j0+=4){
    float4 f = *(const float4*)(src + j0);
    T[(nc+j0+0)*65 + kr] = f2bfr(f.x);
    T[(nc+j0+1)*65 + kr] = f2bfr(f.y);
    T[(nc+j0+2)*65 + kr] = f2bfr(f.z);
    T[(nc+j0+3)*65 + kr] = f2bfr(f.w);
  }
  __syncthreads();
  const int nr = tid>>2, kc = (tid&3)*16;
  bf16x8 o0, o1;
  #pragma unroll
  for (int j=0;j<8;j++){ o0[j] = (short)T[nr*65 + kc + j];
                         o1[j] = (short)T[nr*65 + kc + 8 + j]; }
  *(bf16x8*)&WT[(size_t)(rowOff+n0+nr)*K + k0 + kc]     = o0;
  *(bf16x8*)&WT[(size_t)(rowOff+n0+nr)*K + k0 + kc + 8] = o1;
}

__global__ void concat_bias(const float* __restrict__ a,
                            const float* __restrict__ b,
                            const float* __restrict__ c,
                            float* __restrict__ d){
  int i = blockIdx.x*256 + threadIdx.x;
  d[i] = (i < D_) ? a[i] : (i < 2*D_) ? b[i-D_] : c[i-2*D_];
}

// ---------------- GEMM: C[M][N] = A[M][K] * Bt[N][K]^T, BK=64, swizzled LDS ----------------
// EPI 0: bf16 store ; 1: bf16 gelu store ; 2: resid_f32 += v ; 3: f32 store
template<int EPI>
__global__ __launch_bounds__(256) void gemm_bt(const unsigned short* __restrict__ A,
                                               const unsigned short* __restrict__ Bt,
                                               const float* __restrict__ bias,
                                               unsigned short* __restrict__ Cb,
                                               float* __restrict__ Cf,
                                               int K, int ldc){
  __shared__ unsigned short As[128*64];
  __shared__ unsigned short Bs[128*64];
  const int tid = threadIdx.x;
  const int wave = tid>>6, lane = tid&63;
  // bijective XCD swizzle (all grids here are divisible by 8)
  const int nwg = gridDim.x*gridDim.y;
  const int id  = blockIdx.x + blockIdx.y*gridDim.x;
  const int cpx = nwg>>3;
  const int lg  = (id&7)*cpx + (id>>3);
  const int m0 = (lg % gridDim.x)*128, n0 = (lg / gridDim.x)*128;
  const int wr = wave>>1, wc = wave&1;
  const unsigned short* Ab = A + (size_t)m0*K;
  const unsigned short* Bb = Bt + (size_t)n0*K;
  f32x4 acc[4][4] = {};
  // staging: chunk ci = i*256+tid holds (row=ci>>3, kchunk c=(ci&7)^(row&7))
  int srow[4], sk[4];
  #pragma unroll
  for (int i=0;i<4;i++){
    int ci = i*256 + tid;
    srow[i] = ci>>3;
    sk[i]   = ((ci&7) ^ (srow[i]&7))*8;
  }
  for (int kt=0; kt<K; kt+=64){
    __syncthreads();
    #pragma unroll
    for (int i=0;i<4;i++){
      gl_lds16(Ab + (size_t)srow[i]*K + kt + sk[i], As + i*2048 + wave*512);
      gl_lds16(Bb + (size_t)srow[i]*K + kt + sk[i], Bs + i*2048 + wave*512);
    }
    __syncthreads();
    #pragma unroll
    for (int ks=0; ks<2; ks++){
      bf16x8 af[4], bfv[4];
      #pragma unroll
      for (int mi=0;mi<4;mi++){
        int row = wr*64 + mi*16 + (lane&15);
        int ch  = (ks*4 + (lane>>4)) ^ (row&7);
        af[mi] = *(const bf16x8*)&As[row*64 + ch*8];
      }
      #pragma unroll
      for (int ni=0;ni<4;ni++){
        int row = wc*64 + ni*16 + (lane&15);
        int ch  = (ks*4 + (lane>>4)) ^ (row&7);
        bfv[ni] = *(const bf16x8*)&Bs[row*64 + ch*8];
      }
      #pragma unroll
      for (int mi=0;mi<4;mi++)
        #pragma unroll
        for (int ni=0;ni<4;ni++)
          acc[mi][ni] = __builtin_amdgcn_mfma_f32_16x16x32_bf16(af[mi], bfv[ni], acc[mi][ni], 0,0,0);
    }
  }
  const int rq = (lane>>4)*4, cq = lane&15;
  #pragma unroll
  for (int mi=0;mi<4;mi++){
    #pragma unroll
    for (int ni=0;ni<4;ni++){
      #pragma unroll
      for (int j=0;j<4;j++){
        int r = m0 + wr*64 + mi*16 + rq + j;
        int c = n0 + wc*64 + ni*16 + cq;
        float v = acc[mi][ni][j] + bias[c];
        if (EPI==0)      Cb[(size_t)r*ldc + c] = f2bfr(v);
        else if (EPI==1) Cb[(size_t)r*ldc + c] = f2bfr(0.5f*v*(1.f+erff(v*0.70710678f)));
        else if (EPI==2) Cf[(size_t)r*D_ + c] += v;
        else             Cf[(size_t)r*ldc + c] = v;
      }
    }
  }
}

// ---------------- flash attention: qkv_bf16[M][3072] -> o_bf16[M][1024] ----------------
__global__ __launch_bounds__(256) void attn_kernel(const unsigned short* __restrict__ qkv,
                                                   unsigned short* __restrict__ o){
  const int qt = gridDim.x - 1 - blockIdx.x;   // biggest blocks dispatch first
  const int bh = blockIdx.y;
  const int b = bh>>4, h = bh&15;
  const int tid = threadIdx.x, wave = tid>>6, lane = tid&63;
  const int ql0 = qt*64;
  __shared__ unsigned short Qs[64*64];   // [q][e], 16B-chunk XOR swizzled
  __shared__ unsigned short Ks[64*64];   // [s][e], swizzled
  __shared__ unsigned short Vt[64*72];   // [e][s], padded
  __shared__ unsigned short Ps[64*72];   // [q][s], padded (per-wave private rows)
  const size_t base = (size_t)b*LSEQ_*QKVW + (size_t)h*E_;
  const unsigned short* qb = qkv + base;
  const unsigned short* kb = qkv + base + D_;
  const unsigned short* vb = qkv + base + 2*D_;
  #pragma unroll
  for (int ii=0; ii<2; ii++){
    int i = wave + ii*4;
    int chunk = i*64 + lane, r = chunk>>3, cc = chunk&7;
    gl_lds16(qb + (size_t)(ql0 + r)*QKVW + ((cc^(r&7))*8), Qs + i*512);
  }
  float m4[4] = {-3e38f,-3e38f,-3e38f,-3e38f};
  float l4[4] = {0.f,0.f,0.f,0.f};
  f32x4 oacc[4] = {};
  const int nkv = qt + 1;
  for (int t=0; t<nkv; t++){
    const int s0 = t*64;
    __syncthreads();
    #pragma unroll
    for (int ii=0; ii<2; ii++){
      int i = wave + ii*4;
      int chunk = i*64 + lane, r = chunk>>3, cc = chunk&7;
      gl_lds16(kb + (size_t)(s0 + r)*QKVW + ((cc^(r&7))*8), Ks + i*512);
    }
    #pragma unroll
    for (int p=0;p<2;p++){
      int e0 = wave*8 + p*32;
      bf16x8 vv = *(const bf16x8*)(vb + (size_t)(s0 + lane)*QKVW + e0);
      #pragma unroll
      for (int j=0;j<8;j++) Vt[(e0+j)*72 + lane] = (unsigned short)vv[j];
    }
    __syncthreads();
    f32x4 sacc[4] = {};
    #pragma unroll
    for (int ks=0; ks<2; ks++){
      int qrow = wave*16 + (lane&15);
      int qc = ks*4 + (lane>>4);
      bf16x8 a = *(const bf16x8*)&Qs[qrow*64 + ((qc^(qrow&7))*8)];
      #pragma unroll
      for (int fc=0; fc<4; fc++){
        int krow = fc*16 + (lane&15);
        bf16x8 bv = *(const bf16x8*)&Ks[krow*64 + ((qc^(krow&7))*8)];
        sacc[fc] = __builtin_amdgcn_mfma_f32_16x16x32_bf16(a, bv, sacc[fc], 0,0,0);
      }
    }
    float rm[4], al[4], rs[4];
    #pragma unroll
    for (int j=0;j<4;j++){
      int rowa = ql0 + wave*16 + (lane>>4)*4 + j;
      float mx = -3e38f;
      #pragma unroll
      for (int fc=0;fc<4;fc++){
        int cola = s0 + fc*16 + (lane&15);
        float sv = sacc[fc][j]*0.125f;
        if (cola > rowa) sv = -3e38f;
        sacc[fc][j] = sv;
        mx = fmaxf(mx, sv);
      }
      rm[j] = mx;
    }
    #pragma unroll
    for (int off=1; off<16; off<<=1)
      #pragma unroll
      for (int j=0;j<4;j++) rm[j] = fmaxf(rm[j], __shfl_xor(rm[j], off));
    #pragma unroll
    for (int j=0;j<4;j++){
      float mn = fmaxf(m4[j], rm[j]);
      al[j] = __expf(m4[j] - mn);
      m4[j] = mn; rs[j] = 0.f;
    }
    #pragma unroll
    for (int fc=0;fc<4;fc++)
      #pragma unroll
      for (int j=0;j<4;j++){
        float pv = __expf(sacc[fc][j] - m4[j]);
        sacc[fc][j] = pv; rs[j] += pv;
      }
    #pragma unroll
    for (int off=1; off<16; off<<=1)
      #pragma unroll
      for (int j=0;j<4;j++) rs[j] += __shfl_xor(rs[j], off);
    #pragma unroll
    for (int j=0;j<4;j++) l4[j] = l4[j]*al[j] + rs[j];
    #pragma unroll
    for (int fc=0;fc<4;fc++)
      #pragma unroll
      for (int j=0;j<4;j++){
        oacc[fc][j] *= al[j];
        Ps[(wave*16 + (lane>>4)*4 + j)*72 + fc*16 + (lane&15)] = f2bfr(sacc[fc][j]);
      }
    #pragma unroll
    for (int ks=0; ks<2; ks++){
      bf16x8 ap = *(const bf16x8*)&Ps[(wave*16 + (lane&15))*72 + ks*32 + (lane>>4)*8];
      #pragma unroll
      for (int fc=0;fc<4;fc++){
        bf16x8 bv = *(const bf16x8*)&Vt[(fc*16 + (lane&15))*72 + ks*32 + (lane>>4)*8];
        oacc[fc] = __builtin_amdgcn_mfma_f32_16x16x32_bf16(ap, bv, oacc[fc], 0,0,0);
      }
    }
  }
  #pragma unroll
  for (int fc=0;fc<4;fc++)
    #pragma unroll
    for (int j=0;j<4;j++){
      int r = ql0 + wave*16 + (lane>>4)*4 + j;
      int c = h*E_ + fc*16 + (lane&15);
      o[((size_t)b*LSEQ_ + r)*D_ + c] = f2bfr(oacc[fc][j] / l4[j]);
    }
}

// ---------------- launcher ----------------
extern "C" void kernel_launch(void* const* d_in, const int* in_sizes, int n_in,
                              void* d_out, int out_size, void* d_ws, size_t ws_size,
                              hipStream_t stream){
  (void)in_sizes; (void)n_in; (void)out_size;
  const int*   tokens = (const int*)d_in[0];
  const float* tok_emb= (const float*)d_in[2];
  const float* pos_emb= (const float*)d_in[3];
  const float* Wq = (const float*)d_in[4];
  const float* bq = (const float*)d_in[5];
  const float* Wk = (const float*)d_in[6];
  const float* bk = (const float*)d_in[7];
  const float* Wv = (const float*)d_in[8];
  const float* bv = (const float*)d_in[9];
  const float* Wo = (const float*)d_in[10];
  const float* bo = (const float*)d_in[11];
  const float* W1 = (const float*)d_in[12];
  const float* b1 = (const float*)d_in[13];
  const float* W2 = (const float*)d_in[14];
  const float* b2 = (const float*)d_in[15];
  const float* ln1g = (const float*)d_in[16];
  const float* ln1b = (const float*)d_in[17];
  const float* ln3g = (const float*)d_in[18];
  const float* ln3b = (const float*)d_in[19];
  const float* lnfg = (const float*)d_in[20];
  const float* lnfb = (const float*)d_in[21];
  const float* Wout = (const float*)d_in[22];
  const float* bout = (const float*)d_in[23];

  char* p = (char*)d_ws;
  float* x             = (float*)p;           p += (size_t)M_*D_*sizeof(float);
  unsigned short* h    = (unsigned short*)p;  p += (size_t)M_*D_*2;
  unsigned short* qkv  = (unsigned short*)p;  p += (size_t)M_*QKVW*2;
  unsigned short* ob   = (unsigned short*)p;  p += (size_t)M_*D_*2;
  unsigned short* ffh  = (unsigned short*)p;  p += (size_t)M_*DF_*2;
  unsigned short* wt   = (unsigned short*)p;  p += (size_t)V_*D_*2;   // reusable WT buffer
  float* bqkv          = (float*)p;           p += (size_t)QKVW*sizeof(float);
  if ((size_t)(p - (char*)d_ws) > ws_size) return;

  embed_kernel<<<M_, 256, 0, stream>>>(tokens, tok_emb, pos_emb, x);
  for (int i=0;i<NL_;i++){
    const size_t wOff  = (size_t)i*D_*D_;
    const size_t w1Off = (size_t)i*D_*DF_;
    transpose_kernel<<<dim3(D_/64, D_/64), 256, 0, stream>>>(Wq + wOff, wt, D_, D_, 0);
    transpose_kernel<<<dim3(D_/64, D_/64), 256, 0, stream>>>(Wk + wOff, wt, D_, D_, D_);
    transpose_kernel<<<dim3(D_/64, D_/64), 256, 0, stream>>>(Wv + wOff, wt, D_, D_, 2*D_);
    concat_bias<<<QKVW/256, 256, 0, stream>>>(bq + i*D_, bk + i*D_, bv + i*D_, bqkv);
    ln_kernel<<<M_, 256, 0, stream>>>(x, ln1g + i*D_, ln1b + i*D_, h);
    gemm_bt<0><<<dim3(M_/128, QKVW/128), 256, 0, stream>>>(h, wt, bqkv, qkv, nullptr, D_, QKVW);
    attn_kernel<<<dim3(LSEQ_/64, B_*H_), 256, 0, stream>>>(qkv, ob);
    transpose_kernel<<<dim3(D_/64, D_/64), 256, 0, stream>>>(Wo + wOff, wt, D_, D_, 0);
    gemm_bt<2><<<dim3(M_/128, D_/128), 256, 0, stream>>>(ob, wt, bo + i*D_, nullptr, x, D_, D_);
    ln_kernel<<<M_, 256, 0, stream>>>(x, ln3g + i*D_, ln3b + i*D_, h);
    transpose_kernel<<<dim3(DF_/64, D_/64), 256, 0, stream>>>(W1 + w1Off, wt, DF_, D_, 0);
    gemm_bt<1><<<dim3(M_/128, DF_/128), 256, 0, stream>>>(h, wt, b1 + i*DF_, ffh, nullptr, D_, DF_);
    transpose_kernel<<<dim3(D_/64, DF_/64), 256, 0, stream>>>(W2 + w1Off, wt, D_, DF_, 0);
    gemm_bt<2><<<dim3(M_/128, D_/128), 256, 0, stream>>>(ffh, wt, b2 + i*D_, nullptr, x, DF_, D_);
  }
  ln_kernel<<<M_, 256, 0, stream>>>(x, lnfg, lnfb, h);
  transpose_kernel<<<dim3(V_/64, D_/64), 256, 0, stream>>>(Wout, wt, V_, D_, 0);
  gemm_bt<3><<<dim3(M_/128, V_/128), 256, 0, stream>>>(h, wt, bout, nullptr, (float*)d_out, D_, V_);
}

// Round 4
// 1589.223 us; speedup vs baseline: 1.0314x; 1.0314x over previous
//
#include <hip/hip_runtime.h>
#include <math.h>

#define D_    1024
#define H_    16
#define E_    64
#define DF_   4096
#define NL_   3
#define V_    32000
#define B_    2
#define LSEQ_ 2048
#define M_    (B_*LSEQ_)     // 4096 rows
#define QKVW  (3*D_)         // 3072

typedef __attribute__((ext_vector_type(8))) short bf16x8;   // 8 bf16 = 4 VGPR (MFMA operand)
typedef __attribute__((ext_vector_type(4))) float f32x4;
typedef __attribute__((ext_vector_type(4))) unsigned short us4_t;

__device__ __forceinline__ float bfr2f(unsigned short u){ return __uint_as_float(((unsigned)u)<<16); }
__device__ __forceinline__ unsigned short f2bfr(float f){
  unsigned u = __float_as_uint(f);
  u += 0x7fffu + ((u>>16)&1u);          // RNE
  return (unsigned short)(u>>16);
}
__device__ __forceinline__ void gl_lds16(const unsigned short* g, unsigned short* l){
  __builtin_amdgcn_global_load_lds((const __attribute__((address_space(1))) void*)g,
                                   (__attribute__((address_space(3))) void*)l, 16, 0, 0);
}

// ---------------- embedding ----------------
__global__ __launch_bounds__(256) void embed_kernel(const int* __restrict__ tokens,
                                                    const float* __restrict__ tok_emb,
                                                    const float* __restrict__ pos_emb,
                                                    float* __restrict__ x){
  const int r = blockIdx.x, tid = threadIdx.x;
  const int l = r & (LSEQ_-1);
  const int t = tokens[r];
  float4 te = ((const float4*)(tok_emb + (size_t)t*D_))[tid];
  float4 pe = ((const float4*)(pos_emb + (size_t)l*D_))[tid];
  float4 o = {te.x+pe.x, te.y+pe.y, te.z+pe.z, te.w+pe.w};
  ((float4*)(x + (size_t)r*D_))[tid] = o;
}

// ---------------- layernorm ----------------
__global__ __launch_bounds__(256) void ln_kernel(const float* __restrict__ x,
                                                 const float* __restrict__ g,
                                                 const float* __restrict__ b,
                                                 unsigned short* __restrict__ h){
  const int r = blockIdx.x, tid = threadIdx.x;
  const int wave = tid>>6, lane = tid&63;
  float4 v = ((const float4*)(x + (size_t)r*D_))[tid];
  float s  = v.x+v.y+v.z+v.w;
  float s2 = v.x*v.x+v.y*v.y+v.z*v.z+v.w*v.w;
  #pragma unroll
  for (int off=1; off<64; off<<=1){ s += __shfl_xor(s,off); s2 += __shfl_xor(s2,off); }
  __shared__ float red[8];
  if (!lane){ red[wave]=s; red[4+wave]=s2; }
  __syncthreads();
  s  = red[0]+red[1]+red[2]+red[3];
  s2 = red[4]+red[5]+red[6]+red[7];
  const float mean = s*(1.f/D_);
  const float var  = s2*(1.f/D_) - mean*mean;
  const float rstd = rsqrtf(var + 1e-5f);
  const int c0 = tid*4;
  float4 gg = ((const float4*)g)[tid];
  float4 bb = ((const float4*)b)[tid];
  us4_t ov;
  ov[0] = f2bfr((v.x-mean)*rstd*gg.x + bb.x);
  ov[1] = f2bfr((v.y-mean)*rstd*gg.y + bb.y);
  ov[2] = f2bfr((v.z-mean)*rstd*gg.z + bb.z);
  ov[3] = f2bfr((v.w-mean)*rstd*gg.w + bb.w);
  *(us4_t*)&h[(size_t)r*D_ + c0] = ov;
}

// ---------------- transpose+cast: W_f32[K][N] -> WT_bf16[(rowOff+n)][k] ----------------
__global__ __launch_bounds__(256) void transpose_kernel(const float* __restrict__ W,
                                                        unsigned short* __restrict__ WT,
                                                        int N, int K, int rowOff){
  __shared__ unsigned short T[64*65];
  const int n0 = blockIdx.x*64, k0 = blockIdx.y*64;
  const int tid = threadIdx.x;
  const int kr = tid>>2, nc = (tid&3)*16;
  const float* src = W + (size_t)(k0+kr)*N + n0 + nc;
  #pragma unroll
  for (int j0=0;j0<16;j0+=4){
    float4 f = *(const float4*)(src + j0);
    T[(nc+j0+0)*65 + kr] = f2bfr(f.x);
    T[(nc+j0+1)*65 + kr] = f2bfr(f.y);
    T[(nc+j0+2)*65 + kr] = f2bfr(f.z);
    T[(nc+j0+3)*65 + kr] = f2bfr(f.w);
  }
  __syncthreads();
  const int nr = tid>>2, kc = (tid&3)*16;
  bf16x8 o0, o1;
  #pragma unroll
  for (int j=0;j<8;j++){ o0[j] = (short)T[nr*65 + kc + j];
                         o1[j] = (short)T[nr*65 + kc + 8 + j]; }
  *(bf16x8*)&WT[(size_t)(rowOff+n0+nr)*K + k0 + kc]     = o0;
  *(bf16x8*)&WT[(size_t)(rowOff+n0+nr)*K + k0 + kc + 8] = o1;
}

__global__ void concat_bias(const float* __restrict__ a,
                            const float* __restrict__ b,
                            const float* __restrict__ c,
                            float* __restrict__ d){
  int i = blockIdx.x*256 + threadIdx.x;
  d[i] = (i < D_) ? a[i] : (i < 2*D_) ? b[i-D_] : c[i-2*D_];
}

// ---------------- GEMM: C[M][N] = A[M][K] * Bt[N][K]^T, BK=64, swizzled LDS ----------------
// Natural dispatch order: with gridDim.x=M/128, block id%8 = bx%8, so each XCD
// permanently owns the same 4 m-tiles (A slice stays L2-resident) and fetches
// each B-panel once. Do NOT remap blocks (round-3 lesson: chunked XCD swizzle
// caused 2x A re-fetch).
// EPI 0: bf16 store ; 1: bf16 gelu store ; 2: resid_f32 += v ; 3: f32 store
template<int EPI>
__global__ __launch_bounds__(256) void gemm_bt(const unsigned short* __restrict__ A,
                                               const unsigned short* __restrict__ Bt,
                                               const float* __restrict__ bias,
                                               unsigned short* __restrict__ Cb,
                                               float* __restrict__ Cf,
                                               int K, int ldc){
  __shared__ unsigned short As[128*64];
  __shared__ unsigned short Bs[128*64];
  const int tid = threadIdx.x;
  const int wave = tid>>6, lane = tid&63;
  const int m0 = blockIdx.x*128, n0 = blockIdx.y*128;
  const int wr = wave>>1, wc = wave&1;
  const unsigned short* Ab = A + (size_t)m0*K;
  const unsigned short* Bb = Bt + (size_t)n0*K;
  f32x4 acc[4][4] = {};
  // staging: chunk ci = i*256+tid holds (row=ci>>3, kchunk c=(ci&7)^(row&7))
  int srow[4], sk[4];
  #pragma unroll
  for (int i=0;i<4;i++){
    int ci = i*256 + tid;
    srow[i] = ci>>3;
    sk[i]   = ((ci&7) ^ (srow[i]&7))*8;
  }
  for (int kt=0; kt<K; kt+=64){
    __syncthreads();
    #pragma unroll
    for (int i=0;i<4;i++){
      gl_lds16(Ab + (size_t)srow[i]*K + kt + sk[i], As + i*2048 + wave*512);
      gl_lds16(Bb + (size_t)srow[i]*K + kt + sk[i], Bs + i*2048 + wave*512);
    }
    __syncthreads();
    #pragma unroll
    for (int ks=0; ks<2; ks++){
      bf16x8 af[4], bfv[4];
      #pragma unroll
      for (int mi=0;mi<4;mi++){
        int row = wr*64 + mi*16 + (lane&15);
        int ch  = (ks*4 + (lane>>4)) ^ (row&7);
        af[mi] = *(const bf16x8*)&As[row*64 + ch*8];
      }
      #pragma unroll
      for (int ni=0;ni<4;ni++){
        int row = wc*64 + ni*16 + (lane&15);
        int ch  = (ks*4 + (lane>>4)) ^ (row&7);
        bfv[ni] = *(const bf16x8*)&Bs[row*64 + ch*8];
      }
      #pragma unroll
      for (int mi=0;mi<4;mi++)
        #pragma unroll
        for (int ni=0;ni<4;ni++)
          acc[mi][ni] = __builtin_amdgcn_mfma_f32_16x16x32_bf16(af[mi], bfv[ni], acc[mi][ni], 0,0,0);
    }
  }
  const int rq = (lane>>4)*4, cq = lane&15;
  #pragma unroll
  for (int mi=0;mi<4;mi++){
    #pragma unroll
    for (int ni=0;ni<4;ni++){
      #pragma unroll
      for (int j=0;j<4;j++){
        int r = m0 + wr*64 + mi*16 + rq + j;
        int c = n0 + wc*64 + ni*16 + cq;
        float v = acc[mi][ni][j] + bias[c];
        if (EPI==0)      Cb[(size_t)r*ldc + c] = f2bfr(v);
        else if (EPI==1) Cb[(size_t)r*ldc + c] = f2bfr(0.5f*v*(1.f+erff(v*0.70710678f)));
        else if (EPI==2) Cf[(size_t)r*D_ + c] += v;
        else             Cf[(size_t)r*ldc + c] = v;
      }
    }
  }
}

// ---------------- flash attention: qkv_bf16[M][3072] -> o_bf16[M][1024] ----------------
__global__ __launch_bounds__(256) void attn_kernel(const unsigned short* __restrict__ qkv,
                                                   unsigned short* __restrict__ o){
  const int qt = gridDim.x - 1 - blockIdx.x;   // biggest blocks dispatch first
  const int bh = blockIdx.y;
  const int b = bh>>4, h = bh&15;
  const int tid = threadIdx.x, wave = tid>>6, lane = tid&63;
  const int ql0 = qt*64;
  __shared__ unsigned short Qs[64*64];   // [q][e], 16B-chunk XOR swizzled
  __shared__ unsigned short Ks[64*64];   // [s][e], swizzled
  __shared__ unsigned short Vt[64*72];   // [e][s], padded
  __shared__ unsigned short Ps[64*72];   // [q][s], padded (per-wave private rows)
  const size_t base = (size_t)b*LSEQ_*QKVW + (size_t)h*E_;
  const unsigned short* qb = qkv + base;
  const unsigned short* kb = qkv + base + D_;
  const unsigned short* vb = qkv + base + 2*D_;
  #pragma unroll
  for (int ii=0; ii<2; ii++){
    int i = wave + ii*4;
    int chunk = i*64 + lane, r = chunk>>3, cc = chunk&7;
    gl_lds16(qb + (size_t)(ql0 + r)*QKVW + ((cc^(r&7))*8), Qs + i*512);
  }
  float m4[4] = {-3e38f,-3e38f,-3e38f,-3e38f};
  float l4[4] = {0.f,0.f,0.f,0.f};
  f32x4 oacc[4] = {};
  const int nkv = qt + 1;
  for (int t=0; t<nkv; t++){
    const int s0 = t*64;
    __syncthreads();
    #pragma unroll
    for (int ii=0; ii<2; ii++){
      int i = wave + ii*4;
      int chunk = i*64 + lane, r = chunk>>3, cc = chunk&7;
      gl_lds16(kb + (size_t)(s0 + r)*QKVW + ((cc^(r&7))*8), Ks + i*512);
    }
    #pragma unroll
    for (int p=0;p<2;p++){
      int e0 = wave*8 + p*32;
      bf16x8 vv = *(const bf16x8*)(vb + (size_t)(s0 + lane)*QKVW + e0);
      #pragma unroll
      for (int j=0;j<8;j++) Vt[(e0+j)*72 + lane] = (unsigned short)vv[j];
    }
    __syncthreads();
    f32x4 sacc[4] = {};
    #pragma unroll
    for (int ks=0; ks<2; ks++){
      int qrow = wave*16 + (lane&15);
      int qc = ks*4 + (lane>>4);
      bf16x8 a = *(const bf16x8*)&Qs[qrow*64 + ((qc^(qrow&7))*8)];
      #pragma unroll
      for (int fc=0; fc<4; fc++){
        int krow = fc*16 + (lane&15);
        bf16x8 bv = *(const bf16x8*)&Ks[krow*64 + ((qc^(krow&7))*8)];
        sacc[fc] = __builtin_amdgcn_mfma_f32_16x16x32_bf16(a, bv, sacc[fc], 0,0,0);
      }
    }
    float rm[4], al[4], rs[4];
    #pragma unroll
    for (int j=0;j<4;j++){
      int rowa = ql0 + wave*16 + (lane>>4)*4 + j;
      float mx = -3e38f;
      #pragma unroll
      for (int fc=0;fc<4;fc++){
        int cola = s0 + fc*16 + (lane&15);
        float sv = sacc[fc][j]*0.125f;
        if (cola > rowa) sv = -3e38f;
        sacc[fc][j] = sv;
        mx = fmaxf(mx, sv);
      }
      rm[j] = mx;
    }
    #pragma unroll
    for (int off=1; off<16; off<<=1)
      #pragma unroll
      for (int j=0;j<4;j++) rm[j] = fmaxf(rm[j], __shfl_xor(rm[j], off));
    #pragma unroll
    for (int j=0;j<4;j++){
      float mn = fmaxf(m4[j], rm[j]);
      al[j] = __expf(m4[j] - mn);
      m4[j] = mn; rs[j] = 0.f;
    }
    #pragma unroll
    for (int fc=0;fc<4;fc++)
      #pragma unroll
      for (int j=0;j<4;j++){
        float pv = __expf(sacc[fc][j] - m4[j]);
        sacc[fc][j] = pv; rs[j] += pv;
      }
    #pragma unroll
    for (int off=1; off<16; off<<=1)
      #pragma unroll
      for (int j=0;j<4;j++) rs[j] += __shfl_xor(rs[j], off);
    #pragma unroll
    for (int j=0;j<4;j++) l4[j] = l4[j]*al[j] + rs[j];
    #pragma unroll
    for (int fc=0;fc<4;fc++)
      #pragma unroll
      for (int j=0;j<4;j++){
        oacc[fc][j] *= al[j];
        Ps[(wave*16 + (lane>>4)*4 + j)*72 + fc*16 + (lane&15)] = f2bfr(sacc[fc][j]);
      }
    #pragma unroll
    for (int ks=0; ks<2; ks++){
      bf16x8 ap = *(const bf16x8*)&Ps[(wave*16 + (lane&15))*72 + ks*32 + (lane>>4)*8];
      #pragma unroll
      for (int fc=0;fc<4;fc++){
        bf16x8 bv = *(const bf16x8*)&Vt[(fc*16 + (lane&15))*72 + ks*32 + (lane>>4)*8];
        oacc[fc] = __builtin_amdgcn_mfma_f32_16x16x32_bf16(ap, bv, oacc[fc], 0,0,0);
      }
    }
  }
  #pragma unroll
  for (int fc=0;fc<4;fc++)
    #pragma unroll
    for (int j=0;j<4;j++){
      int r = ql0 + wave*16 + (lane>>4)*4 + j;
      int c = h*E_ + fc*16 + (lane&15);
      o[((size_t)b*LSEQ_ + r)*D_ + c] = f2bfr(oacc[fc][j] / l4[j]);
    }
}

// ---------------- launcher ----------------
extern "C" void kernel_launch(void* const* d_in, const int* in_sizes, int n_in,
                              void* d_out, int out_size, void* d_ws, size_t ws_size,
                              hipStream_t stream){
  (void)in_sizes; (void)n_in; (void)out_size;
  const int*   tokens = (const int*)d_in[0];
  const float* tok_emb= (const float*)d_in[2];
  const float* pos_emb= (const float*)d_in[3];
  const float* Wq = (const float*)d_in[4];
  const float* bq = (const float*)d_in[5];
  const float* Wk = (const float*)d_in[6];
  const float* bk = (const float*)d_in[7];
  const float* Wv = (const float*)d_in[8];
  const float* bv = (const float*)d_in[9];
  const float* Wo = (const float*)d_in[10];
  const float* bo = (const float*)d_in[11];
  const float* W1 = (const float*)d_in[12];
  const float* b1 = (const float*)d_in[13];
  const float* W2 = (const float*)d_in[14];
  const float* b2 = (const float*)d_in[15];
  const float* ln1g = (const float*)d_in[16];
  const float* ln1b = (const float*)d_in[17];
  const float* ln3g = (const float*)d_in[18];
  const float* ln3b = (const float*)d_in[19];
  const float* lnfg = (const float*)d_in[20];
  const float* lnfb = (const float*)d_in[21];
  const float* Wout = (const float*)d_in[22];
  const float* bout = (const float*)d_in[23];

  char* p = (char*)d_ws;
  float* x             = (float*)p;           p += (size_t)M_*D_*sizeof(float);
  unsigned short* h    = (unsigned short*)p;  p += (size_t)M_*D_*2;
  unsigned short* qkv  = (unsigned short*)p;  p += (size_t)M_*QKVW*2;
  unsigned short* ob   = (unsigned short*)p;  p += (size_t)M_*D_*2;
  unsigned short* ffh  = (unsigned short*)p;  p += (size_t)M_*DF_*2;
  unsigned short* wt   = (unsigned short*)p;  p += (size_t)V_*D_*2;   // reusable WT buffer
  float* bqkv          = (float*)p;           p += (size_t)QKVW*sizeof(float);
  if ((size_t)(p - (char*)d_ws) > ws_size) return;

  embed_kernel<<<M_, 256, 0, stream>>>(tokens, tok_emb, pos_emb, x);
  for (int i=0;i<NL_;i++){
    const size_t wOff  = (size_t)i*D_*D_;
    const size_t w1Off = (size_t)i*D_*DF_;
    transpose_kernel<<<dim3(D_/64, D_/64), 256, 0, stream>>>(Wq + wOff, wt, D_, D_, 0);
    transpose_kernel<<<dim3(D_/64, D_/64), 256, 0, stream>>>(Wk + wOff, wt, D_, D_, D_);
    transpose_kernel<<<dim3(D_/64, D_/64), 256, 0, stream>>>(Wv + wOff, wt, D_, D_, 2*D_);
    concat_bias<<<QKVW/256, 256, 0, stream>>>(bq + i*D_, bk + i*D_, bv + i*D_, bqkv);
    ln_kernel<<<M_, 256, 0, stream>>>(x, ln1g + i*D_, ln1b + i*D_, h);
    gemm_bt<0><<<dim3(M_/128, QKVW/128), 256, 0, stream>>>(h, wt, bqkv, qkv, nullptr, D_, QKVW);
    attn_kernel<<<dim3(LSEQ_/64, B_*H_), 256, 0, stream>>>(qkv, ob);
    transpose_kernel<<<dim3(D_/64, D_/64), 256, 0, stream>>>(Wo + wOff, wt, D_, D_, 0);
    gemm_bt<2><<<dim3(M_/128, D_/128), 256, 0, stream>>>(ob, wt, bo + i*D_, nullptr, x, D_, D_);
    ln_kernel<<<M_, 256, 0, stream>>>(x, ln3g + i*D_, ln3b + i*D_, h);
    transpose_kernel<<<dim3(DF_/64, D_/64), 256, 0, stream>>>(W1 + w1Off, wt, DF_, D_, 0);
    gemm_bt<1><<<dim3(M_/128, DF_/128), 256, 0, stream>>>(h, wt, b1 + i*DF_, ffh, nullptr, D_, DF_);
    transpose_kernel<<<dim3(D_/64, DF_/64), 256, 0, stream>>>(W2 + w1Off, wt, D_, DF_, 0);
    gemm_bt<2><<<dim3(M_/128, D_/128), 256, 0, stream>>>(ffh, wt, b2 + i*D_, nullptr, x, DF_, D_);
  }
  ln_kernel<<<M_, 256, 0, stream>>>(x, lnfg, lnfb, h);
  transpose_kernel<<<dim3(V_/64, D_/64), 256, 0, stream>>>(Wout, wt, V_, D_, 0);
  gemm_bt<3><<<dim3(M_/128, V_/128), 256, 0, stream>>>(h, wt, bout, nullptr, (float*)d_out, D_, V_);
}

// Round 5
// 1427.956 us; speedup vs baseline: 1.1479x; 1.1129x over previous
//
#include <hip/hip_runtime.h>
#include <math.h>

#define D_    1024
#define H_    16
#define E_    64
#define DF_   4096
#define NL_   3
#define V_    32000
#define B_    2
#define LSEQ_ 2048
#define M_    (B_*LSEQ_)     // 4096 rows
#define QKVW  (3*D_)         // 3072

typedef __attribute__((ext_vector_type(8))) short bf16x8;   // 8 bf16 = 4 VGPR (MFMA operand)
typedef __attribute__((ext_vector_type(4))) float f32x4;
typedef __attribute__((ext_vector_type(4))) unsigned short us4_t;

__device__ __forceinline__ float bfr2f(unsigned short u){ return __uint_as_float(((unsigned)u)<<16); }
__device__ __forceinline__ unsigned short f2bfr(float f){
  unsigned u = __float_as_uint(f);
  u += 0x7fffu + ((u>>16)&1u);          // RNE
  return (unsigned short)(u>>16);
}
__device__ __forceinline__ void gl_lds16(const unsigned short* g, unsigned short* l){
  __builtin_amdgcn_global_load_lds((const __attribute__((address_space(1))) void*)g,
                                   (__attribute__((address_space(3))) void*)l, 16, 0, 0);
}

// ---------------- embedding ----------------
__global__ __launch_bounds__(256) void embed_kernel(const int* __restrict__ tokens,
                                                    const float* __restrict__ tok_emb,
                                                    const float* __restrict__ pos_emb,
                                                    float* __restrict__ x){
  const int r = blockIdx.x, tid = threadIdx.x;
  const int l = r & (LSEQ_-1);
  const int t = tokens[r];
  float4 te = ((const float4*)(tok_emb + (size_t)t*D_))[tid];
  float4 pe = ((const float4*)(pos_emb + (size_t)l*D_))[tid];
  float4 o = {te.x+pe.x, te.y+pe.y, te.z+pe.z, te.w+pe.w};
  ((float4*)(x + (size_t)r*D_))[tid] = o;
}

// ---------------- layernorm ----------------
__global__ __launch_bounds__(256) void ln_kernel(const float* __restrict__ x,
                                                 const float* __restrict__ g,
                                                 const float* __restrict__ b,
                                                 unsigned short* __restrict__ h){
  const int r = blockIdx.x, tid = threadIdx.x;
  const int wave = tid>>6, lane = tid&63;
  float4 v = ((const float4*)(x + (size_t)r*D_))[tid];
  float s  = v.x+v.y+v.z+v.w;
  float s2 = v.x*v.x+v.y*v.y+v.z*v.z+v.w*v.w;
  #pragma unroll
  for (int off=1; off<64; off<<=1){ s += __shfl_xor(s,off); s2 += __shfl_xor(s2,off); }
  __shared__ float red[8];
  if (!lane){ red[wave]=s; red[4+wave]=s2; }
  __syncthreads();
  s  = red[0]+red[1]+red[2]+red[3];
  s2 = red[4]+red[5]+red[6]+red[7];
  const float mean = s*(1.f/D_);
  const float var  = s2*(1.f/D_) - mean*mean;
  const float rstd = rsqrtf(var + 1e-5f);
  const int c0 = tid*4;
  float4 gg = ((const float4*)g)[tid];
  float4 bb = ((const float4*)b)[tid];
  us4_t ov;
  ov[0] = f2bfr((v.x-mean)*rstd*gg.x + bb.x);
  ov[1] = f2bfr((v.y-mean)*rstd*gg.y + bb.y);
  ov[2] = f2bfr((v.z-mean)*rstd*gg.z + bb.z);
  ov[3] = f2bfr((v.w-mean)*rstd*gg.w + bb.w);
  *(us4_t*)&h[(size_t)r*D_ + c0] = ov;
}

// ---------------- transpose+cast: W_f32[K][N] -> WT_bf16[(rowOff+n)][k] ----------------
__global__ __launch_bounds__(256) void transpose_kernel(const float* __restrict__ W,
                                                        unsigned short* __restrict__ WT,
                                                        int N, int K, int rowOff){
  __shared__ unsigned short T[64*65];
  const int n0 = blockIdx.x*64, k0 = blockIdx.y*64;
  const int tid = threadIdx.x;
  const int kr = tid>>2, nc = (tid&3)*16;
  const float* src = W + (size_t)(k0+kr)*N + n0 + nc;
  #pragma unroll
  for (int j0=0;j0<16;j0+=4){
    float4 f = *(const float4*)(src + j0);
    T[(nc+j0+0)*65 + kr] = f2bfr(f.x);
    T[(nc+j0+1)*65 + kr] = f2bfr(f.y);
    T[(nc+j0+2)*65 + kr] = f2bfr(f.z);
    T[(nc+j0+3)*65 + kr] = f2bfr(f.w);
  }
  __syncthreads();
  const int nr = tid>>2, kc = (tid&3)*16;
  bf16x8 o0, o1;
  #pragma unroll
  for (int j=0;j<8;j++){ o0[j] = (short)T[nr*65 + kc + j];
                         o1[j] = (short)T[nr*65 + kc + 8 + j]; }
  *(bf16x8*)&WT[(size_t)(rowOff+n0+nr)*K + k0 + kc]     = o0;
  *(bf16x8*)&WT[(size_t)(rowOff+n0+nr)*K + k0 + kc + 8] = o1;
}

__global__ void concat_bias(const float* __restrict__ a,
                            const float* __restrict__ b,
                            const float* __restrict__ c,
                            float* __restrict__ d){
  int i = blockIdx.x*256 + threadIdx.x;
  d[i] = (i < D_) ? a[i] : (i < 2*D_) ? b[i-D_] : c[i-2*D_];
}

// ---------------- 128^2 2-phase GEMM (kept for N=1024 outputs: Wo, W2) ----------------
// EPI 2 only: resid_f32 += v
template<int EPI>
__global__ __launch_bounds__(256) void gemm_bt(const unsigned short* __restrict__ A,
                                               const unsigned short* __restrict__ Bt,
                                               const float* __restrict__ bias,
                                               unsigned short* __restrict__ Cb,
                                               float* __restrict__ Cf,
                                               int K, int ldc){
  __shared__ unsigned short As[128*64];
  __shared__ unsigned short Bs[128*64];
  const int tid = threadIdx.x;
  const int wave = tid>>6, lane = tid&63;
  const int m0 = blockIdx.x*128, n0 = blockIdx.y*128;
  const int wr = wave>>1, wc = wave&1;
  const unsigned short* Ab = A + (size_t)m0*K;
  const unsigned short* Bb = Bt + (size_t)n0*K;
  f32x4 acc[4][4] = {};
  int srow[4], sk[4];
  #pragma unroll
  for (int i=0;i<4;i++){
    int ci = i*256 + tid;
    srow[i] = ci>>3;
    sk[i]   = ((ci&7) ^ (srow[i]&7))*8;
  }
  for (int kt=0; kt<K; kt+=64){
    __syncthreads();
    #pragma unroll
    for (int i=0;i<4;i++){
      gl_lds16(Ab + (size_t)srow[i]*K + kt + sk[i], As + i*2048 + wave*512);
      gl_lds16(Bb + (size_t)srow[i]*K + kt + sk[i], Bs + i*2048 + wave*512);
    }
    __syncthreads();
    #pragma unroll
    for (int ks=0; ks<2; ks++){
      bf16x8 af[4], bfv[4];
      #pragma unroll
      for (int mi=0;mi<4;mi++){
        int row = wr*64 + mi*16 + (lane&15);
        int ch  = (ks*4 + (lane>>4)) ^ (row&7);
        af[mi] = *(const bf16x8*)&As[row*64 + ch*8];
      }
      #pragma unroll
      for (int ni=0;ni<4;ni++){
        int row = wc*64 + ni*16 + (lane&15);
        int ch  = (ks*4 + (lane>>4)) ^ (row&7);
        bfv[ni] = *(const bf16x8*)&Bs[row*64 + ch*8];
      }
      #pragma unroll
      for (int mi=0;mi<4;mi++)
        #pragma unroll
        for (int ni=0;ni<4;ni++)
          acc[mi][ni] = __builtin_amdgcn_mfma_f32_16x16x32_bf16(af[mi], bfv[ni], acc[mi][ni], 0,0,0);
    }
  }
  const int rq = (lane>>4)*4, cq = lane&15;
  #pragma unroll
  for (int mi=0;mi<4;mi++){
    #pragma unroll
    for (int ni=0;ni<4;ni++){
      #pragma unroll
      for (int j=0;j<4;j++){
        int r = m0 + wr*64 + mi*16 + rq + j;
        int c = n0 + wc*64 + ni*16 + cq;
        float v = acc[mi][ni][j] + bias[c];
        if (EPI==2) Cf[(size_t)r*D_ + c] += v;
        else        Cf[(size_t)r*ldc + c] = v;
      }
    }
  }
}

// ---------------- 256^2 8-phase GEMM (T2+T3+T4+T5), for N%256==0 ----------------
// 512 threads = 8 waves (2M x 4N). Per-wave out 128x64. BK=64. LDS 128 KB.
// Counted vmcnt: T+1's A staged in ph1-2, T+2's B staged in ph3-4; boundary
// wait vmcnt(4) leaves only T+2's B (newest 4 loads) in flight. Raw s_barrier
// everywhere (NOT __syncthreads - that drains vmcnt).
// EPI 0: bf16 store ; 1: bf16 gelu store ; 3: f32 store
#define GBAR()  do{ __builtin_amdgcn_s_barrier(); __builtin_amdgcn_sched_barrier(0); }while(0)
#define GPHASE(P, STAGE_STMT, TAIL_STMT) do{                                        \
    bf16x8 afr[2][2];                                                               \
    _Pragma("unroll")                                                               \
    for (int mi=0;mi<2;mi++){                                                       \
      _Pragma("unroll")                                                             \
      for (int ks=0;ks<2;ks++){                                                     \
        int row = wr*128 + (P)*32 + mi*16 + (lane&15);                              \
        int ch  = (ks*4 + (lane>>4)) ^ (row&7);                                     \
        afr[mi][ks] = *(const bf16x8*)&Alds[row*64 + ch*8];                         \
      } }                                                                           \
    STAGE_STMT;                                                                     \
    GBAR();                                                                         \
    __builtin_amdgcn_s_setprio(1);                                                  \
    _Pragma("unroll")                                                               \
    for (int ks=0;ks<2;ks++){                                                       \
      _Pragma("unroll")                                                             \
      for (int mi=0;mi<2;mi++){                                                     \
        _Pragma("unroll")                                                           \
        for (int ni=0;ni<4;ni++)                                                    \
          acc[(P)*2+mi][ni] = __builtin_amdgcn_mfma_f32_16x16x32_bf16(              \
              afr[mi][ks], bfr[ni][ks], acc[(P)*2+mi][ni], 0,0,0);                  \
      } }                                                                           \
    __builtin_amdgcn_s_setprio(0);                                                  \
    __builtin_amdgcn_sched_barrier(0);                                              \
    TAIL_STMT;                                                                      \
    GBAR();                                                                         \
  }while(0)

template<int EPI>
__global__ __launch_bounds__(512, 2) void gemm256(const unsigned short* __restrict__ A,
                                                  const unsigned short* __restrict__ Bt,
                                                  const float* __restrict__ bias,
                                                  unsigned short* __restrict__ Cb,
                                                  float* __restrict__ Cf,
                                                  int K, int ldc){
  __shared__ unsigned short lds[2][2][256*64];   // [buf][A/B][row*64 + chunk*8]
  const int tid = threadIdx.x, wave = tid>>6, lane = tid&63;
  const int m0 = blockIdx.x*256, n0 = blockIdx.y*256;
  const int wr = wave>>2, wc = wave&3;
  const unsigned short* Ab = A  + (size_t)m0*K;
  const unsigned short* Bb = Bt + (size_t)n0*K;
  // staging geometry: chunk ci in a 128-row half holds k-chunk (ci&7)^(row&7)
  int srow[2], scol[2];
  #pragma unroll
  for (int i=0;i<2;i++){
    int ci = i*512 + tid;
    srow[i] = ci>>3;
    scol[i] = ((ci&7) ^ (srow[i]&7))*8;
  }
  auto stageA = [&](int tbuf, int hh, int kt){
    #pragma unroll
    for (int i=0;i<2;i++)
      gl_lds16(Ab + (size_t)(hh*128+srow[i])*K + kt + scol[i],
               &lds[tbuf][0][hh*8192 + (i*512+tid)*8]);
  };
  auto stageB = [&](int tbuf, int hh, int kt){
    #pragma unroll
    for (int i=0;i<2;i++)
      gl_lds16(Bb + (size_t)(hh*128+srow[i])*K + kt + scol[i],
               &lds[tbuf][1][hh*8192 + (i*512+tid)*8]);
  };
  f32x4 acc[8][4] = {};
  const int NT = K>>6;          // callers guarantee NT >= 3
  // prologue: T0 fully + T1's B; wait all-but-newest-4
  stageB(0,0,0); stageB(0,1,0);
  stageA(0,0,0); stageA(0,1,0);
  stageB(1,0,64); stageB(1,1,64);
  asm volatile("s_waitcnt vmcnt(4)" ::: "memory");
  __builtin_amdgcn_sched_barrier(0);
  GBAR();
  for (int t=0; t<NT; ++t){
    const int buf = t&1, bufn = buf^1;
    const unsigned short* Alds = &lds[buf][0][0];
    const unsigned short* Blds = &lds[buf][1][0];
    const int ktA = (t+1)<<6, ktB = (t+2)<<6;
    const bool s1 = (t+1)<NT, s2 = (t+2)<NT;
    // B fragments for the whole tile (read once, ph1)
    bf16x8 bfr[4][2];
    #pragma unroll
    for (int ni=0;ni<4;ni++)
      #pragma unroll
      for (int ks=0;ks<2;ks++){
        int row = wc*64 + ni*16 + (lane&15);
        int ch  = (ks*4 + (lane>>4)) ^ (row&7);
        bfr[ni][ks] = *(const bf16x8*)&Blds[row*64 + ch*8];
      }
    GPHASE(0, if (s1) stageA(bufn,0,ktA), ((void)0));
    GPHASE(1, if (s1) stageA(bufn,1,ktA), ((void)0));
    GPHASE(2, if (s2) stageB(buf,0,ktB), ((void)0));
    GPHASE(3, if (s2) stageB(buf,1,ktB),
           if (s2){ asm volatile("s_waitcnt vmcnt(4)" ::: "memory"); }
           else   { asm volatile("s_waitcnt vmcnt(0)" ::: "memory"); }
           __builtin_amdgcn_sched_barrier(0));
  }
  // epilogue
  const int rq = (lane>>4)*4, cq = lane&15;
  #pragma unroll
  for (int mi=0;mi<8;mi++){
    #pragma unroll
    for (int ni=0;ni<4;ni++){
      #pragma unroll
      for (int j=0;j<4;j++){
        int r = m0 + wr*128 + mi*16 + rq + j;
        int c = n0 + wc*64 + ni*16 + cq;
        float v = acc[mi][ni][j] + bias[c];
        if (EPI==0)      Cb[(size_t)r*ldc + c] = f2bfr(v);
        else if (EPI==1) Cb[(size_t)r*ldc + c] = f2bfr(0.5f*v*(1.f+erff(v*0.70710678f)));
        else             Cf[(size_t)r*ldc + c] = v;
      }
    }
  }
}

// ---------------- flash attention: qkv_bf16[M][3072] -> o_bf16[M][1024] ----------------
__global__ __launch_bounds__(256) void attn_kernel(const unsigned short* __restrict__ qkv,
                                                   unsigned short* __restrict__ o){
  const int qt = gridDim.x - 1 - blockIdx.x;   // biggest blocks dispatch first
  const int bh = blockIdx.y;
  const int b = bh>>4, h = bh&15;
  const int tid = threadIdx.x, wave = tid>>6, lane = tid&63;
  const int ql0 = qt*64;
  __shared__ unsigned short Qs[64*64];   // [q][e], 16B-chunk XOR swizzled
  __shared__ unsigned short Ks[64*64];   // [s][e], swizzled
  __shared__ unsigned short Vt[64*72];   // [e][s], padded
  __shared__ unsigned short Ps[64*72];   // [q][s], padded (per-wave private rows)
  const size_t base = (size_t)b*LSEQ_*QKVW + (size_t)h*E_;
  const unsigned short* qb = qkv + base;
  const unsigned short* kb = qkv + base + D_;
  const unsigned short* vb = qkv + base + 2*D_;
  #pragma unroll
  for (int ii=0; ii<2; ii++){
    int i = wave + ii*4;
    int chunk = i*64 + lane, r = chunk>>3, cc = chunk&7;
    gl_lds16(qb + (size_t)(ql0 + r)*QKVW + ((cc^(r&7))*8), Qs + i*512);
  }
  float m4[4] = {-3e38f,-3e38f,-3e38f,-3e38f};
  float l4[4] = {0.f,0.f,0.f,0.f};
  f32x4 oacc[4] = {};
  const int nkv = qt + 1;
  for (int t=0; t<nkv; t++){
    const int s0 = t*64;
    __syncthreads();
    #pragma unroll
    for (int ii=0; ii<2; ii++){
      int i = wave + ii*4;
      int chunk = i*64 + lane, r = chunk>>3, cc = chunk&7;
      gl_lds16(kb + (size_t)(s0 + r)*QKVW + ((cc^(r&7))*8), Ks + i*512);
    }
    #pragma unroll
    for (int p=0;p<2;p++){
      int e0 = wave*8 + p*32;
      bf16x8 vv = *(const bf16x8*)(vb + (size_t)(s0 + lane)*QKVW + e0);
      #pragma unroll
      for (int j=0;j<8;j++) Vt[(e0+j)*72 + lane] = (unsigned short)vv[j];
    }
    __syncthreads();
    f32x4 sacc[4] = {};
    #pragma unroll
    for (int ks=0; ks<2; ks++){
      int qrow = wave*16 + (lane&15);
      int qc = ks*4 + (lane>>4);
      bf16x8 a = *(const bf16x8*)&Qs[qrow*64 + ((qc^(qrow&7))*8)];
      #pragma unroll
      for (int fc=0; fc<4; fc++){
        int krow = fc*16 + (lane&15);
        bf16x8 bv = *(const bf16x8*)&Ks[krow*64 + ((qc^(krow&7))*8)];
        sacc[fc] = __builtin_amdgcn_mfma_f32_16x16x32_bf16(a, bv, sacc[fc], 0,0,0);
      }
    }
    float rm[4], al[4], rs[4];
    #pragma unroll
    for (int j=0;j<4;j++){
      int rowa = ql0 + wave*16 + (lane>>4)*4 + j;
      float mx = -3e38f;
      #pragma unroll
      for (int fc=0;fc<4;fc++){
        int cola = s0 + fc*16 + (lane&15);
        float sv = sacc[fc][j]*0.125f;
        if (cola > rowa) sv = -3e38f;
        sacc[fc][j] = sv;
        mx = fmaxf(mx, sv);
      }
      rm[j] = mx;
    }
    #pragma unroll
    for (int off=1; off<16; off<<=1)
      #pragma unroll
      for (int j=0;j<4;j++) rm[j] = fmaxf(rm[j], __shfl_xor(rm[j], off));
    #pragma unroll
    for (int j=0;j<4;j++){
      float mn = fmaxf(m4[j], rm[j]);
      al[j] = __expf(m4[j] - mn);
      m4[j] = mn; rs[j] = 0.f;
    }
    #pragma unroll
    for (int fc=0;fc<4;fc++)
      #pragma unroll
      for (int j=0;j<4;j++){
        float pv = __expf(sacc[fc][j] - m4[j]);
        sacc[fc][j] = pv; rs[j] += pv;
      }
    #pragma unroll
    for (int off=1; off<16; off<<=1)
      #pragma unroll
      for (int j=0;j<4;j++) rs[j] += __shfl_xor(rs[j], off);
    #pragma unroll
    for (int j=0;j<4;j++) l4[j] = l4[j]*al[j] + rs[j];
    #pragma unroll
    for (int fc=0;fc<4;fc++)
      #pragma unroll
      for (int j=0;j<4;j++){
        oacc[fc][j] *= al[j];
        Ps[(wave*16 + (lane>>4)*4 + j)*72 + fc*16 + (lane&15)] = f2bfr(sacc[fc][j]);
      }
    #pragma unroll
    for (int ks=0; ks<2; ks++){
      bf16x8 ap = *(const bf16x8*)&Ps[(wave*16 + (lane&15))*72 + ks*32 + (lane>>4)*8];
      #pragma unroll
      for (int fc=0;fc<4;fc++){
        bf16x8 bv = *(const bf16x8*)&Vt[(fc*16 + (lane&15))*72 + ks*32 + (lane>>4)*8];
        oacc[fc] = __builtin_amdgcn_mfma_f32_16x16x32_bf16(ap, bv, oacc[fc], 0,0,0);
      }
    }
  }
  #pragma unroll
  for (int fc=0;fc<4;fc++)
    #pragma unroll
    for (int j=0;j<4;j++){
      int r = ql0 + wave*16 + (lane>>4)*4 + j;
      int c = h*E_ + fc*16 + (lane&15);
      o[((size_t)b*LSEQ_ + r)*D_ + c] = f2bfr(oacc[fc][j] / l4[j]);
    }
}

// ---------------- launcher ----------------
extern "C" void kernel_launch(void* const* d_in, const int* in_sizes, int n_in,
                              void* d_out, int out_size, void* d_ws, size_t ws_size,
                              hipStream_t stream){
  (void)in_sizes; (void)n_in; (void)out_size;
  const int*   tokens = (const int*)d_in[0];
  const float* tok_emb= (const float*)d_in[2];
  const float* pos_emb= (const float*)d_in[3];
  const float* Wq = (const float*)d_in[4];
  const float* bq = (const float*)d_in[5];
  const float* Wk = (const float*)d_in[6];
  const float* bk = (const float*)d_in[7];
  const float* Wv = (const float*)d_in[8];
  const float* bv = (const float*)d_in[9];
  const float* Wo = (const float*)d_in[10];
  const float* bo = (const float*)d_in[11];
  const float* W1 = (const float*)d_in[12];
  const float* b1 = (const float*)d_in[13];
  const float* W2 = (const float*)d_in[14];
  const float* b2 = (const float*)d_in[15];
  const float* ln1g = (const float*)d_in[16];
  const float* ln1b = (const float*)d_in[17];
  const float* ln3g = (const float*)d_in[18];
  const float* ln3b = (const float*)d_in[19];
  const float* lnfg = (const float*)d_in[20];
  const float* lnfb = (const float*)d_in[21];
  const float* Wout = (const float*)d_in[22];
  const float* bout = (const float*)d_in[23];

  char* p = (char*)d_ws;
  float* x             = (float*)p;           p += (size_t)M_*D_*sizeof(float);
  unsigned short* h    = (unsigned short*)p;  p += (size_t)M_*D_*2;
  unsigned short* qkv  = (unsigned short*)p;  p += (size_t)M_*QKVW*2;
  unsigned short* ob   = (unsigned short*)p;  p += (size_t)M_*D_*2;
  unsigned short* ffh  = (unsigned short*)p;  p += (size_t)M_*DF_*2;
  unsigned short* wt   = (unsigned short*)p;  p += (size_t)V_*D_*2;   // reusable WT buffer
  float* bqkv          = (float*)p;           p += (size_t)QKVW*sizeof(float);
  if ((size_t)(p - (char*)d_ws) > ws_size) return;

  embed_kernel<<<M_, 256, 0, stream>>>(tokens, tok_emb, pos_emb, x);
  for (int i=0;i<NL_;i++){
    const size_t wOff  = (size_t)i*D_*D_;
    const size_t w1Off = (size_t)i*D_*DF_;
    transpose_kernel<<<dim3(D_/64, D_/64), 256, 0, stream>>>(Wq + wOff, wt, D_, D_, 0);
    transpose_kernel<<<dim3(D_/64, D_/64), 256, 0, stream>>>(Wk + wOff, wt, D_, D_, D_);
    transpose_kernel<<<dim3(D_/64, D_/64), 256, 0, stream>>>(Wv + wOff, wt, D_, D_, 2*D_);
    concat_bias<<<QKVW/256, 256, 0, stream>>>(bq + i*D_, bk + i*D_, bv + i*D_, bqkv);
    ln_kernel<<<M_, 256, 0, stream>>>(x, ln1g + i*D_, ln1b + i*D_, h);
    gemm256<0><<<dim3(M_/256, QKVW/256), 512, 0, stream>>>(h, wt, bqkv, qkv, nullptr, D_, QKVW);
    attn_kernel<<<dim3(LSEQ_/64, B_*H_), 256, 0, stream>>>(qkv, ob);
    transpose_kernel<<<dim3(D_/64, D_/64), 256, 0, stream>>>(Wo + wOff, wt, D_, D_, 0);
    gemm_bt<2><<<dim3(M_/128, D_/128), 256, 0, stream>>>(ob, wt, bo + i*D_, nullptr, x, D_, D_);
    ln_kernel<<<M_, 256, 0, stream>>>(x, ln3g + i*D_, ln3b + i*D_, h);
    transpose_kernel<<<dim3(DF_/64, D_/64), 256, 0, stream>>>(W1 + w1Off, wt, DF_, D_, 0);
    gemm256<1><<<dim3(M_/256, DF_/256), 512, 0, stream>>>(h, wt, b1 + i*DF_, ffh, nullptr, D_, DF_);
    transpose_kernel<<<dim3(D_/64, DF_/64), 256, 0, stream>>>(W2 + w1Off, wt, D_, DF_, 0);
    gemm_bt<2><<<dim3(M_/128, D_/128), 256, 0, stream>>>(ffh, wt, b2 + i*D_, nullptr, x, DF_, D_);
  }
  ln_kernel<<<M_, 256, 0, stream>>>(x, lnfg, lnfb, h);
  transpose_kernel<<<dim3(V_/64, D_/64), 256, 0, stream>>>(Wout, wt, V_, D_, 0);
  gemm256<3><<<dim3(M_/256, V_/256), 512, 0, stream>>>(h, wt, bout, nullptr, (float*)d_out, D_, V_);
}

// Round 6
// 1394.479 us; speedup vs baseline: 1.1755x; 1.0240x over previous
//
#include <hip/hip_runtime.h>
#include <math.h>

#define D_    1024
#define H_    16
#define E_    64
#define DF_   4096
#define NL_   3
#define V_    32000
#define B_    2
#define LSEQ_ 2048
#define M_    (B_*LSEQ_)     // 4096 rows
#define QKVW  (3*D_)         // 3072

typedef __attribute__((ext_vector_type(8))) short bf16x8;   // 8 bf16 = 4 VGPR (MFMA operand)
typedef __attribute__((ext_vector_type(4))) float f32x4;
typedef __attribute__((ext_vector_type(4))) unsigned short us4_t;

__device__ __forceinline__ float bfr2f(unsigned short u){ return __uint_as_float(((unsigned)u)<<16); }
__device__ __forceinline__ unsigned short f2bfr(float f){
  unsigned u = __float_as_uint(f);
  u += 0x7fffu + ((u>>16)&1u);          // RNE
  return (unsigned short)(u>>16);
}
__device__ __forceinline__ void gl_lds16(const unsigned short* g, unsigned short* l){
  __builtin_amdgcn_global_load_lds((const __attribute__((address_space(1))) void*)g,
                                   (__attribute__((address_space(3))) void*)l, 16, 0, 0);
}

// ---------------- embedding ----------------
__global__ __launch_bounds__(256) void embed_kernel(const int* __restrict__ tokens,
                                                    const float* __restrict__ tok_emb,
                                                    const float* __restrict__ pos_emb,
                                                    float* __restrict__ x){
  const int r = blockIdx.x, tid = threadIdx.x;
  const int l = r & (LSEQ_-1);
  const int t = tokens[r];
  float4 te = ((const float4*)(tok_emb + (size_t)t*D_))[tid];
  float4 pe = ((const float4*)(pos_emb + (size_t)l*D_))[tid];
  float4 o = {te.x+pe.x, te.y+pe.y, te.z+pe.z, te.w+pe.w};
  ((float4*)(x + (size_t)r*D_))[tid] = o;
}

// ---------------- layernorm ----------------
__global__ __launch_bounds__(256) void ln_kernel(const float* __restrict__ x,
                                                 const float* __restrict__ g,
                                                 const float* __restrict__ b,
                                                 unsigned short* __restrict__ h){
  const int r = blockIdx.x, tid = threadIdx.x;
  const int wave = tid>>6, lane = tid&63;
  float4 v = ((const float4*)(x + (size_t)r*D_))[tid];
  float s  = v.x+v.y+v.z+v.w;
  float s2 = v.x*v.x+v.y*v.y+v.z*v.z+v.w*v.w;
  #pragma unroll
  for (int off=1; off<64; off<<=1){ s += __shfl_xor(s,off); s2 += __shfl_xor(s2,off); }
  __shared__ float red[8];
  if (!lane){ red[wave]=s; red[4+wave]=s2; }
  __syncthreads();
  s  = red[0]+red[1]+red[2]+red[3];
  s2 = red[4]+red[5]+red[6]+red[7];
  const float mean = s*(1.f/D_);
  const float var  = s2*(1.f/D_) - mean*mean;
  const float rstd = rsqrtf(var + 1e-5f);
  const int c0 = tid*4;
  float4 gg = ((const float4*)g)[tid];
  float4 bb = ((const float4*)b)[tid];
  us4_t ov;
  ov[0] = f2bfr((v.x-mean)*rstd*gg.x + bb.x);
  ov[1] = f2bfr((v.y-mean)*rstd*gg.y + bb.y);
  ov[2] = f2bfr((v.z-mean)*rstd*gg.z + bb.z);
  ov[3] = f2bfr((v.w-mean)*rstd*gg.w + bb.w);
  *(us4_t*)&h[(size_t)r*D_ + c0] = ov;
}

// ---------------- transpose+cast: W_f32[K][N] -> WT_bf16[(rowOff+n)][k] ----------------
__global__ __launch_bounds__(256) void transpose_kernel(const float* __restrict__ W,
                                                        unsigned short* __restrict__ WT,
                                                        int N, int K, int rowOff){
  __shared__ unsigned short T[64*65];
  const int n0 = blockIdx.x*64, k0 = blockIdx.y*64;
  const int tid = threadIdx.x;
  // read: 16 lanes cover 256 B contiguous per row (coalesced)
  const int rr = tid>>4, c4 = (tid&15)*4;
  #pragma unroll
  for (int pp=0; pp<4; pp++){
    int row = pp*16 + rr;
    float4 f = *(const float4*)(W + (size_t)(k0+row)*N + n0 + c4);
    T[(c4+0)*65 + row] = f2bfr(f.x);
    T[(c4+1)*65 + row] = f2bfr(f.y);
    T[(c4+2)*65 + row] = f2bfr(f.z);
    T[(c4+3)*65 + row] = f2bfr(f.w);
  }
  __syncthreads();
  const int nr = tid>>2, kc = (tid&3)*16;
  bf16x8 o0, o1;
  #pragma unroll
  for (int j=0;j<8;j++){ o0[j] = (short)T[nr*65 + kc + j];
                         o1[j] = (short)T[nr*65 + kc + 8 + j]; }
  *(bf16x8*)&WT[(size_t)(rowOff+n0+nr)*K + k0 + kc]     = o0;
  *(bf16x8*)&WT[(size_t)(rowOff+n0+nr)*K + k0 + kc + 8] = o1;
}

__global__ void concat_bias(const float* __restrict__ a,
                            const float* __restrict__ b,
                            const float* __restrict__ c,
                            float* __restrict__ d){
  int i = blockIdx.x*256 + threadIdx.x;
  d[i] = (i < D_) ? a[i] : (i < 2*D_) ? b[i-D_] : c[i-2*D_];
}

// ---------------- 128^2 2-phase GEMM (N=1024 outputs: Wo, W2) ----------------
template<int EPI>
__global__ __launch_bounds__(256) void gemm_bt(const unsigned short* __restrict__ A,
                                               const unsigned short* __restrict__ Bt,
                                               const float* __restrict__ bias,
                                               unsigned short* __restrict__ Cb,
                                               float* __restrict__ Cf,
                                               int K, int ldc){
  __shared__ unsigned short As[128*64];
  __shared__ unsigned short Bs[128*64];
  const int tid = threadIdx.x;
  const int wave = tid>>6, lane = tid&63;
  const int m0 = blockIdx.x*128, n0 = blockIdx.y*128;
  const int wr = wave>>1, wc = wave&1;
  const unsigned short* Ab = A + (size_t)m0*K;
  const unsigned short* Bb = Bt + (size_t)n0*K;
  f32x4 acc[4][4] = {};
  int srow[4], sk[4];
  #pragma unroll
  for (int i=0;i<4;i++){
    int ci = i*256 + tid;
    srow[i] = ci>>3;
    sk[i]   = ((ci&7) ^ (srow[i]&7))*8;
  }
  for (int kt=0; kt<K; kt+=64){
    __syncthreads();
    #pragma unroll
    for (int i=0;i<4;i++){
      gl_lds16(Ab + (size_t)srow[i]*K + kt + sk[i], As + i*2048 + wave*512);
      gl_lds16(Bb + (size_t)srow[i]*K + kt + sk[i], Bs + i*2048 + wave*512);
    }
    __syncthreads();
    #pragma unroll
    for (int ks=0; ks<2; ks++){
      bf16x8 af[4], bfv[4];
      #pragma unroll
      for (int mi=0;mi<4;mi++){
        int row = wr*64 + mi*16 + (lane&15);
        int ch  = (ks*4 + (lane>>4)) ^ (row&7);
        af[mi] = *(const bf16x8*)&As[row*64 + ch*8];
      }
      #pragma unroll
      for (int ni=0;ni<4;ni++){
        int row = wc*64 + ni*16 + (lane&15);
        int ch  = (ks*4 + (lane>>4)) ^ (row&7);
        bfv[ni] = *(const bf16x8*)&Bs[row*64 + ch*8];
      }
      #pragma unroll
      for (int mi=0;mi<4;mi++)
        #pragma unroll
        for (int ni=0;ni<4;ni++)
          acc[mi][ni] = __builtin_amdgcn_mfma_f32_16x16x32_bf16(af[mi], bfv[ni], acc[mi][ni], 0,0,0);
    }
  }
  const int rq = (lane>>4)*4, cq = lane&15;
  #pragma unroll
  for (int mi=0;mi<4;mi++){
    #pragma unroll
    for (int ni=0;ni<4;ni++){
      #pragma unroll
      for (int j=0;j<4;j++){
        int r = m0 + wr*64 + mi*16 + rq + j;
        int c = n0 + wc*64 + ni*16 + cq;
        float v = acc[mi][ni][j] + bias[c];
        if (EPI==2) Cf[(size_t)r*D_ + c] += v;
        else        Cf[(size_t)r*ldc + c] = v;
      }
    }
  }
}

// ---------------- 256^2 8-phase GEMM (T2+T3+T4+T5), N%256==0 ----------------
// Barriers: 1 leading per phase + 1 boundary = 5 per K-tile (trailing barriers
// removed after hazard analysis: stage targets disjoint from live reads; bfr
// consumed in ph1 before ph3's lead barrier can be passed).
#define GBAR()  do{ __builtin_amdgcn_s_barrier(); __builtin_amdgcn_sched_barrier(0); }while(0)
#define GPHASE(P, STAGE_STMT, TAIL_STMT) do{                                        \
    bf16x8 afr[2][2];                                                               \
    _Pragma("unroll")                                                               \
    for (int mi=0;mi<2;mi++){                                                       \
      _Pragma("unroll")                                                             \
      for (int ks=0;ks<2;ks++){                                                     \
        int row = wr*128 + (P)*32 + mi*16 + (lane&15);                              \
        int ch  = (ks*4 + (lane>>4)) ^ (row&7);                                     \
        afr[mi][ks] = *(const bf16x8*)&Alds[row*64 + ch*8];                         \
      } }                                                                           \
    STAGE_STMT;                                                                     \
    GBAR();                                                                         \
    __builtin_amdgcn_s_setprio(1);                                                  \
    _Pragma("unroll")                                                               \
    for (int ks=0;ks<2;ks++){                                                       \
      _Pragma("unroll")                                                             \
      for (int mi=0;mi<2;mi++){                                                     \
        _Pragma("unroll")                                                           \
        for (int ni=0;ni<4;ni++)                                                    \
          acc[(P)*2+mi][ni] = __builtin_amdgcn_mfma_f32_16x16x32_bf16(              \
              afr[mi][ks], bfr[ni][ks], acc[(P)*2+mi][ni], 0,0,0);                  \
      } }                                                                           \
    __builtin_amdgcn_s_setprio(0);                                                  \
    __builtin_amdgcn_sched_barrier(0);                                              \
    TAIL_STMT;                                                                      \
  }while(0)

template<int EPI>
__global__ __launch_bounds__(512, 2) void gemm256(const unsigned short* __restrict__ A,
                                                  const unsigned short* __restrict__ Bt,
                                                  const float* __restrict__ bias,
                                                  unsigned short* __restrict__ Cb,
                                                  float* __restrict__ Cf,
                                                  int K, int ldc){
  __shared__ unsigned short lds[2][2][256*64];   // [buf][A/B][row*64 + chunk*8]
  const int tid = threadIdx.x, wave = tid>>6, lane = tid&63;
  const int m0 = blockIdx.x*256, n0 = blockIdx.y*256;
  const int wr = wave>>2, wc = wave&3;
  const unsigned short* Ab = A  + (size_t)m0*K;
  const unsigned short* Bb = Bt + (size_t)n0*K;
  int srow[2], scol[2];
  #pragma unroll
  for (int i=0;i<2;i++){
    int ci = i*512 + tid;
    srow[i] = ci>>3;
    scol[i] = ((ci&7) ^ (srow[i]&7))*8;
  }
  auto stageA = [&](int tbuf, int hh, int kt){
    #pragma unroll
    for (int i=0;i<2;i++)
      gl_lds16(Ab + (size_t)(hh*128+srow[i])*K + kt + scol[i],
               &lds[tbuf][0][hh*8192 + (i*512+tid)*8]);
  };
  auto stageB = [&](int tbuf, int hh, int kt){
    #pragma unroll
    for (int i=0;i<2;i++)
      gl_lds16(Bb + (size_t)(hh*128+srow[i])*K + kt + scol[i],
               &lds[tbuf][1][hh*8192 + (i*512+tid)*8]);
  };
  f32x4 acc[8][4] = {};
  const int NT = K>>6;          // callers guarantee NT >= 3
  stageB(0,0,0); stageB(0,1,0);
  stageA(0,0,0); stageA(0,1,0);
  stageB(1,0,64); stageB(1,1,64);
  asm volatile("s_waitcnt vmcnt(4)" ::: "memory");
  __builtin_amdgcn_sched_barrier(0);
  GBAR();
  for (int t=0; t<NT; ++t){
    const int buf = t&1, bufn = buf^1;
    const unsigned short* Alds = &lds[buf][0][0];
    const unsigned short* Blds = &lds[buf][1][0];
    const int ktA = (t+1)<<6, ktB = (t+2)<<6;
    const bool s1 = (t+1)<NT, s2 = (t+2)<NT;
    bf16x8 bfr[4][2];
    #pragma unroll
    for (int ni=0;ni<4;ni++)
      #pragma unroll
      for (int ks=0;ks<2;ks++){
        int row = wc*64 + ni*16 + (lane&15);
        int ch  = (ks*4 + (lane>>4)) ^ (row&7);
        bfr[ni][ks] = *(const bf16x8*)&Blds[row*64 + ch*8];
      }
    GPHASE(0, if (s1) stageA(bufn,0,ktA), ((void)0));
    GPHASE(1, if (s1) stageA(bufn,1,ktA), ((void)0));
    GPHASE(2, if (s2) stageB(buf,0,ktB), ((void)0));
    GPHASE(3, if (s2) stageB(buf,1,ktB),
           { if (s2){ asm volatile("s_waitcnt vmcnt(4)" ::: "memory"); }
             else   { asm volatile("s_waitcnt vmcnt(0)" ::: "memory"); }
             __builtin_amdgcn_sched_barrier(0);
             GBAR(); });
  }
  const int rq = (lane>>4)*4, cq = lane&15;
  #pragma unroll
  for (int mi=0;mi<8;mi++){
    #pragma unroll
    for (int ni=0;ni<4;ni++){
      #pragma unroll
      for (int j=0;j<4;j++){
        int r = m0 + wr*128 + mi*16 + rq + j;
        int c = n0 + wc*64 + ni*16 + cq;
        float v = acc[mi][ni][j] + bias[c];
        if (EPI==0)      Cb[(size_t)r*ldc + c] = f2bfr(v);
        else if (EPI==1) Cb[(size_t)r*ldc + c] = f2bfr(0.5f*v*(1.f+erff(v*0.70710678f)));
        else             Cf[(size_t)r*ldc + c] = v;
      }
    }
  }
}

// ---------------- flash attention: QBLK=128, 8 waves ----------------
__global__ __launch_bounds__(512) void attn_kernel(const unsigned short* __restrict__ qkv,
                                                   unsigned short* __restrict__ o){
  const int qt = gridDim.x - 1 - blockIdx.x;   // biggest blocks dispatch first
  const int bh = blockIdx.y;
  const int b = bh>>4, h = bh&15;
  const int tid = threadIdx.x, wave = tid>>6, lane = tid&63;
  const int ql0 = qt*128;
  __shared__ unsigned short Qs[128*64];  // [q][e], 16B-chunk XOR swizzled
  __shared__ unsigned short Ks[64*64];   // [s][e], swizzled
  __shared__ unsigned short Vt[64*72];   // [e][s], padded
  __shared__ unsigned short Ps[128*72];  // [q][s], padded (per-wave private rows)
  const size_t base = (size_t)b*LSEQ_*QKVW + (size_t)h*E_;
  const unsigned short* qb = qkv + base;
  const unsigned short* kb = qkv + base + D_;
  const unsigned short* vb = qkv + base + 2*D_;
  #pragma unroll
  for (int ii=0; ii<2; ii++){
    int i = wave + ii*8;
    int chunk = i*64 + lane, r = chunk>>3, cc = chunk&7;
    gl_lds16(qb + (size_t)(ql0 + r)*QKVW + ((cc^(r&7))*8), Qs + i*512);
  }
  float m4[4] = {-3e38f,-3e38f,-3e38f,-3e38f};
  float l4[4] = {0.f,0.f,0.f,0.f};
  f32x4 oacc[4] = {};
  const int nkv = qt*2 + 2;
  for (int t=0; t<nkv; t++){
    const int s0 = t*64;
    __syncthreads();
    { // K: 512 chunks, 1 per thread
      int chunk = wave*64 + lane, r = chunk>>3, cc = chunk&7;
      gl_lds16(kb + (size_t)(s0 + r)*QKVW + ((cc^(r&7))*8), Ks + wave*512);
    }
    { // V transposed: lane = s, wave owns e-slice [wave*8, wave*8+8)
      int e0 = wave*8;
      bf16x8 vv = *(const bf16x8*)(vb + (size_t)(s0 + lane)*QKVW + e0);
      #pragma unroll
      for (int j=0;j<8;j++) Vt[(e0+j)*72 + lane] = (unsigned short)vv[j];
    }
    __syncthreads();
    // S = Q K^T (wave owns q-rows [wave*16, wave*16+16))
    f32x4 sacc[4] = {};
    #pragma unroll
    for (int ks=0; ks<2; ks++){
      int qrow = wave*16 + (lane&15);
      int qc = ks*4 + (lane>>4);
      bf16x8 a = *(const bf16x8*)&Qs[qrow*64 + ((qc^(qrow&7))*8)];
      #pragma unroll
      for (int fc=0; fc<4; fc++){
        int krow = fc*16 + (lane&15);
        bf16x8 bv = *(const bf16x8*)&Ks[krow*64 + ((qc^(krow&7))*8)];
        sacc[fc] = __builtin_amdgcn_mfma_f32_16x16x32_bf16(a, bv, sacc[fc], 0,0,0);
      }
    }
    // online softmax with defer-max (THR=8)
    float rm[4];
    #pragma unroll
    for (int j=0;j<4;j++){
      int rowa = ql0 + wave*16 + (lane>>4)*4 + j;
      float mx = -3e38f;
      #pragma unroll
      for (int fc=0;fc<4;fc++){
        int cola = s0 + fc*16 + (lane&15);
        float sv = sacc[fc][j]*0.125f;
        if (cola > rowa) sv = -3e38f;
        sacc[fc][j] = sv;
        mx = fmaxf(mx, sv);
      }
      rm[j] = mx;
    }
    #pragma unroll
    for (int off=1; off<16; off<<=1)
      #pragma unroll
      for (int j=0;j<4;j++) rm[j] = fmaxf(rm[j], __shfl_xor(rm[j], off));
    bool need = (rm[0]>m4[0]+8.f)||(rm[1]>m4[1]+8.f)||(rm[2]>m4[2]+8.f)||(rm[3]>m4[3]+8.f);
    const bool rescale = (__ballot(need) != 0ull);
    float al[4] = {1.f,1.f,1.f,1.f};
    if (rescale){
      #pragma unroll
      for (int j=0;j<4;j++){
        float mn = fmaxf(m4[j], rm[j]);
        al[j] = __expf(m4[j] - mn);
        m4[j] = mn;
      }
    }
    float rs[4] = {0.f,0.f,0.f,0.f};
    #pragma unroll
    for (int fc=0;fc<4;fc++)
      #pragma unroll
      for (int j=0;j<4;j++){
        float pv = __expf(sacc[fc][j] - m4[j]);
        rs[j] += pv;
        // truncating f32->bf16 (P in [0,e^8]; bias cancels in PV/l ratio)
        Ps[(wave*16 + (lane>>4)*4 + j)*72 + fc*16 + (lane&15)] =
            (unsigned short)(__float_as_uint(pv)>>16);
      }
    #pragma unroll
    for (int off=1; off<16; off<<=1)
      #pragma unroll
      for (int j=0;j<4;j++) rs[j] += __shfl_xor(rs[j], off);
    if (rescale){
      #pragma unroll
      for (int j=0;j<4;j++){
        l4[j] = l4[j]*al[j] + rs[j];
        #pragma unroll
        for (int fc=0;fc<4;fc++) oacc[fc][j] *= al[j];
      }
    } else {
      #pragma unroll
      for (int j=0;j<4;j++) l4[j] += rs[j];
    }
    // O += P V  (Ps rows wave-private: no barrier)
    #pragma unroll
    for (int ks=0; ks<2; ks++){
      bf16x8 ap = *(const bf16x8*)&Ps[(wave*16 + (lane&15))*72 + ks*32 + (lane>>4)*8];
      #pragma unroll
      for (int fc=0;fc<4;fc++){
        bf16x8 bv = *(const bf16x8*)&Vt[(fc*16 + (lane&15))*72 + ks*32 + (lane>>4)*8];
        oacc[fc] = __builtin_amdgcn_mfma_f32_16x16x32_bf16(ap, bv, oacc[fc], 0,0,0);
      }
    }
  }
  #pragma unroll
  for (int fc=0;fc<4;fc++)
    #pragma unroll
    for (int j=0;j<4;j++){
      int r = ql0 + wave*16 + (lane>>4)*4 + j;
      int c = h*E_ + fc*16 + (lane&15);
      o[((size_t)b*LSEQ_ + r)*D_ + c] = f2bfr(oacc[fc][j] / l4[j]);
    }
}

// ---------------- launcher ----------------
extern "C" void kernel_launch(void* const* d_in, const int* in_sizes, int n_in,
                              void* d_out, int out_size, void* d_ws, size_t ws_size,
                              hipStream_t stream){
  (void)in_sizes; (void)n_in; (void)out_size;
  const int*   tokens = (const int*)d_in[0];
  const float* tok_emb= (const float*)d_in[2];
  const float* pos_emb= (const float*)d_in[3];
  const float* Wq = (const float*)d_in[4];
  const float* bq = (const float*)d_in[5];
  const float* Wk = (const float*)d_in[6];
  const float* bk = (const float*)d_in[7];
  const float* Wv = (const float*)d_in[8];
  const float* bv = (const float*)d_in[9];
  const float* Wo = (const float*)d_in[10];
  const float* bo = (const float*)d_in[11];
  const float* W1 = (const float*)d_in[12];
  const float* b1 = (const float*)d_in[13];
  const float* W2 = (const float*)d_in[14];
  const float* b2 = (const float*)d_in[15];
  const float* ln1g = (const float*)d_in[16];
  const float* ln1b = (const float*)d_in[17];
  const float* ln3g = (const float*)d_in[18];
  const float* ln3b = (const float*)d_in[19];
  const float* lnfg = (const float*)d_in[20];
  const float* lnfb = (const float*)d_in[21];
  const float* Wout = (const float*)d_in[22];
  const float* bout = (const float*)d_in[23];

  char* p = (char*)d_ws;
  float* x             = (float*)p;           p += (size_t)M_*D_*sizeof(float);
  unsigned short* h    = (unsigned short*)p;  p += (size_t)M_*D_*2;
  unsigned short* qkv  = (unsigned short*)p;  p += (size_t)M_*QKVW*2;
  unsigned short* ob   = (unsigned short*)p;  p += (size_t)M_*D_*2;
  unsigned short* ffh  = (unsigned short*)p;  p += (size_t)M_*DF_*2;
  unsigned short* wt   = (unsigned short*)p;  p += (size_t)V_*D_*2;   // reusable WT buffer
  float* bqkv          = (float*)p;           p += (size_t)QKVW*sizeof(float);
  if ((size_t)(p - (char*)d_ws) > ws_size) return;

  embed_kernel<<<M_, 256, 0, stream>>>(tokens, tok_emb, pos_emb, x);
  for (int i=0;i<NL_;i++){
    const size_t wOff  = (size_t)i*D_*D_;
    const size_t w1Off = (size_t)i*D_*DF_;
    transpose_kernel<<<dim3(D_/64, D_/64), 256, 0, stream>>>(Wq + wOff, wt, D_, D_, 0);
    transpose_kernel<<<dim3(D_/64, D_/64), 256, 0, stream>>>(Wk + wOff, wt, D_, D_, D_);
    transpose_kernel<<<dim3(D_/64, D_/64), 256, 0, stream>>>(Wv + wOff, wt, D_, D_, 2*D_);
    concat_bias<<<QKVW/256, 256, 0, stream>>>(bq + i*D_, bk + i*D_, bv + i*D_, bqkv);
    ln_kernel<<<M_, 256, 0, stream>>>(x, ln1g + i*D_, ln1b + i*D_, h);
    gemm256<0><<<dim3(M_/256, QKVW/256), 512, 0, stream>>>(h, wt, bqkv, qkv, nullptr, D_, QKVW);
    attn_kernel<<<dim3(LSEQ_/128, B_*H_), 512, 0, stream>>>(qkv, ob);
    transpose_kernel<<<dim3(D_/64, D_/64), 256, 0, stream>>>(Wo + wOff, wt, D_, D_, 0);
    gemm_bt<2><<<dim3(M_/128, D_/128), 256, 0, stream>>>(ob, wt, bo + i*D_, nullptr, x, D_, D_);
    ln_kernel<<<M_, 256, 0, stream>>>(x, ln3g + i*D_, ln3b + i*D_, h);
    transpose_kernel<<<dim3(DF_/64, D_/64), 256, 0, stream>>>(W1 + w1Off, wt, DF_, D_, 0);
    gemm256<1><<<dim3(M_/256, DF_/256), 512, 0, stream>>>(h, wt, b1 + i*DF_, ffh, nullptr, D_, DF_);
    transpose_kernel<<<dim3(D_/64, DF_/64), 256, 0, stream>>>(W2 + w1Off, wt, D_, DF_, 0);
    gemm_bt<2><<<dim3(M_/128, D_/128), 256, 0, stream>>>(ffh, wt, b2 + i*D_, nullptr, x, DF_, D_);
  }
  ln_kernel<<<M_, 256, 0, stream>>>(x, lnfg, lnfb, h);
  transpose_kernel<<<dim3(V_/64, D_/64), 256, 0, stream>>>(Wout, wt, V_, D_, 0);
  gemm256<3><<<dim3(M_/256, V_/256), 512, 0, stream>>>(h, wt, bout, nullptr, (float*)d_out, D_, V_);
}